// Round 7
// baseline (250.713 us; speedup 1.0000x reference)
//
#include <hip/hip_runtime.h>
#include <math.h>

#define N_SRC 8192
#define M_TGT 16384
#define REG_P 0.05f
#define LOG2E 1.44269504088896340736f
#define LN2   0.69314718055994530942f

#define QSPLIT 16                 // k2: 128 rowblks x 16 = 2048 blocks

typedef __attribute__((ext_vector_type(8))) short short8;
typedef __attribute__((ext_vector_type(4))) float f32x4;

// Workspace byte offsets
#define OFF_TGT  0u                          // tgt bf16 row-major: 2 MB
#define OFF_SQT  (2u << 20)                  // sq_t[M]: 64 KB
#define OFF_SQS  ((2u << 20) + 65536u)       // sq_s[N]: 32 KB
#define OFF_PART ((2u << 20) + 98304u)       // float2[256] tgt-block partials: 2 KB
#define OFF_ACC  ((2u << 20) + 100352u)      // float accumulator
#define OFF_CNT  ((2u << 20) + 100356u)      // uint done-counter
#define OFF_L    ((2u << 20) + 102400u)      // l partials [QSPLIT][N]: 512 KB

__device__ __forceinline__ unsigned short f2bf(float f) {   // RNE fp32->bf16
    unsigned u = __float_as_uint(f);
    u += 0x7fffu + ((u >> 16) & 1u);
    return (unsigned short)(u >> 16);
}

__device__ __forceinline__ float fast_exp2(float x) {
#if __has_builtin(__builtin_amdgcn_exp2f)
    return __builtin_amdgcn_exp2f(x);
#else
    return exp2f(x);
#endif
}

// k1: pure streaming. Blocks 0..255: convert 64 tgt rows to bf16 row-major
// (fully coalesced both directions), per-row sq_t, per-block (sum sq_t, sum psi).
// Blocks 256..383: sq_s for 64 src rows. Block 0 inits ACC/CNT for k3.
__global__ __launch_bounds__(256) void k1_stage(const float* __restrict__ src,
                                                const float* __restrict__ tgt,
                                                const float* __restrict__ psi,
                                                char* __restrict__ ws) {
    const int tid = threadIdx.x;
    const int b   = blockIdx.x;

    if (b < 256) {
        const int base = b * 4096 + tid * 16;        // float index; 16 floats/thread
        const float4* g = (const float4*)(tgt + base);
        float4 v0 = g[0], v1 = g[1], v2 = g[2], v3 = g[3];
        short8 p0, p1;
        p0[0]=(short)f2bf(v0.x); p0[1]=(short)f2bf(v0.y); p0[2]=(short)f2bf(v0.z); p0[3]=(short)f2bf(v0.w);
        p0[4]=(short)f2bf(v1.x); p0[5]=(short)f2bf(v1.y); p0[6]=(short)f2bf(v1.z); p0[7]=(short)f2bf(v1.w);
        p1[0]=(short)f2bf(v2.x); p1[1]=(short)f2bf(v2.y); p1[2]=(short)f2bf(v2.z); p1[3]=(short)f2bf(v2.w);
        p1[4]=(short)f2bf(v3.x); p1[5]=(short)f2bf(v3.y); p1[6]=(short)f2bf(v3.z); p1[7]=(short)f2bf(v3.w);
        short8* tb = (short8*)(ws + OFF_TGT);
        tb[b * 512 + tid * 2]     = p0;              // unit = base/8, consecutive
        tb[b * 512 + tid * 2 + 1] = p1;

        float sq = v0.x*v0.x + v0.y*v0.y + v0.z*v0.z + v0.w*v0.w
                 + v1.x*v1.x + v1.y*v1.y + v1.z*v1.z + v1.w*v1.w
                 + v2.x*v2.x + v2.y*v2.y + v2.z*v2.z + v2.w*v2.w
                 + v3.x*v3.x + v3.y*v3.y + v3.z*v3.z + v3.w*v3.w;
        float r = sq;
        r += __shfl_xor(r, 1);
        r += __shfl_xor(r, 2);                        // 4 lanes per row
        if ((tid & 3) == 0) ((float*)(ws + OFF_SQT))[b * 64 + (tid >> 2)] = r;

        float ps = (tid < 64) ? psi[b * 64 + tid] : 0.f;
        __shared__ float s0[256], s1[256];
        s0[tid] = sq; s1[tid] = ps;
        __syncthreads();
        for (int off = 128; off > 0; off >>= 1) {
            if (tid < off) { s0[tid] += s0[tid + off]; s1[tid] += s1[tid + off]; }
            __syncthreads();
        }
        if (tid == 0) {
            float2 o; o.x = s0[0]; o.y = s1[0];
            ((float2*)(ws + OFF_PART))[b] = o;
            if (b == 0) {
                *(float*)(ws + OFF_ACC) = 0.f;
                *(unsigned*)(ws + OFF_CNT) = 0u;
            }
        }
    } else {
        const int bb = b - 256;
        const int base = bb * 4096 + tid * 16;
        const float4* g = (const float4*)(src + base);
        float4 v0 = g[0], v1 = g[1], v2 = g[2], v3 = g[3];
        float sq = v0.x*v0.x + v0.y*v0.y + v0.z*v0.z + v0.w*v0.w
                 + v1.x*v1.x + v1.y*v1.y + v1.z*v1.z + v1.w*v1.w
                 + v2.x*v2.x + v2.y*v2.y + v2.z*v2.z + v2.w*v2.w
                 + v3.x*v3.x + v3.y*v3.y + v3.z*v3.z + v3.w*v3.w;
        float r = sq;
        r += __shfl_xor(r, 1);
        r += __shfl_xor(r, 2);
        if ((tid & 3) == 0) ((float*)(ws + OFF_SQS))[bb * 64 + (tid >> 2)] = r;
    }
}

// k2: MFMA GEMM + sum-exp2. 2048 blocks, 64 rows x 1024 cols each; 16 col-tiles
// per wave, depth-1 register prefetch. Bias via MFMA C operand; alpha2 folded
// into bf16 A-fragments. launch_bounds(256,4) caps VGPR at 128 for 4 blocks/CU.
__global__ __launch_bounds__(256, 4) void k2_main(const float* __restrict__ src,
                                                  const float* __restrict__ psi,
                                                  char* __restrict__ ws) {
    const int tid  = threadIdx.x;
    const int lane = tid & 63;
    const int w    = tid >> 6;
    const int lo   = lane & 15;
    const int hi   = lane >> 4;
    const int q      = blockIdx.x & (QSPLIT - 1);
    const int rowblk = blockIdx.x >> 4;
    const int row0   = rowblk * 64;

    __shared__ float s_bias[1024];
    __shared__ float s_l[4][64];

    // sum sq_t from k1 tgt-block partials (256 entries)
    const float2* __restrict__ part = (const float2*)(ws + OFF_PART);
    float ssq = 0.f;
#pragma unroll
    for (int k = 0; k < 4; ++k) ssq += part[k * 64 + lane].x;
#pragma unroll
    for (int off = 1; off < 64; off <<= 1) ssq += __shfl_xor(ssq, off);
    const float inv_cn = (float)M_TGT / ssq;
    const float c_psi  = (1.0f / REG_P) * LOG2E;
    const float c_sqt  = inv_cn * c_psi;
    const float alpha2 = 2.0f * c_sqt;

    // A fragments from global fp32, pre-scaled by alpha2
    short8 Af[4][2];
#pragma unroll
    for (int g = 0; g < 4; ++g)
#pragma unroll
        for (int kk = 0; kk < 2; ++kk) {
            const float* p = src + (size_t)(row0 + g * 16 + lo) * 64 + kk * 32 + hi * 8;
            float4 u0 = ((const float4*)p)[0];
            float4 u1 = ((const float4*)p)[1];
            short8 pk;
            pk[0]=(short)f2bf(alpha2*u0.x); pk[1]=(short)f2bf(alpha2*u0.y);
            pk[2]=(short)f2bf(alpha2*u0.z); pk[3]=(short)f2bf(alpha2*u0.w);
            pk[4]=(short)f2bf(alpha2*u1.x); pk[5]=(short)f2bf(alpha2*u1.y);
            pk[6]=(short)f2bf(alpha2*u1.z); pk[7]=(short)f2bf(alpha2*u1.w);
            Af[g][kk] = pk;
        }

    // bias table for this block's 1024 cols
    {
        const float* SQT = (const float*)(ws + OFF_SQT);
        const int j0 = q * 1024 + tid * 4;
        float4 sa = *(const float4*)(SQT + j0);
        float4 pa = *(const float4*)(psi + j0);
        float4 o0;
        o0.x = pa.x * c_psi - sa.x * c_sqt;  o0.y = pa.y * c_psi - sa.y * c_sqt;
        o0.z = pa.z * c_psi - sa.z * c_sqt;  o0.w = pa.w * c_psi - sa.w * c_sqt;
        *(float4*)&s_bias[tid * 4] = o0;
    }
    __syncthreads();

    float lsum[4][4];
#pragma unroll
    for (int g = 0; g < 4; ++g)
#pragma unroll
        for (int r = 0; r < 4; ++r) lsum[g][r] = 0.f;

    // B fragments from row-major bf16: unit = (row)*8 + kk*4 + hi, row = T*16+lo
    const short8* __restrict__ TB = (const short8*)(ws + OFF_TGT);
    const int Tbase = q * 64 + w * 16;            // this wave's 16 col-tiles
    const int ub    = (Tbase * 16 + lo) * 8 + hi; // lane's base unit
    const int colb  = w * 256 + lo;               // LDS bias base

    short8 B0n = TB[ub];
    short8 B1n = TB[ub + 4];
    float  bln = s_bias[colb];

    for (int t = 0; t < 16; ++t) {
        short8 B0 = B0n, B1 = B1n;
        float  bl = bln;
        if (t < 15) {
            B0n = TB[ub + (t + 1) * 128];
            B1n = TB[ub + (t + 1) * 128 + 4];
            bln = s_bias[colb + (t + 1) * 16];
        }
        f32x4 bias4 = {bl, bl, bl, bl};   // C operand: bias per col (col = lane&15)
        f32x4 acc[4];
#pragma unroll
        for (int g = 0; g < 4; ++g) {
            f32x4 a = __builtin_amdgcn_mfma_f32_16x16x32_bf16(Af[g][0], B0, bias4, 0, 0, 0);
            a       = __builtin_amdgcn_mfma_f32_16x16x32_bf16(Af[g][1], B1, a,     0, 0, 0);
            acc[g] = a;
        }
#pragma unroll
        for (int g = 0; g < 4; ++g)
#pragma unroll
            for (int r = 0; r < 4; ++r)
                lsum[g][r] += fast_exp2(acc[g][r]);
    }

    // reduce over 16 col-lanes per row; combine 4 waves via LDS; write q-slice
#pragma unroll
    for (int g = 0; g < 4; ++g)
#pragma unroll
        for (int r = 0; r < 4; ++r) {
            float v = lsum[g][r];
            v += __shfl_xor(v, 1); v += __shfl_xor(v, 2);
            v += __shfl_xor(v, 4); v += __shfl_xor(v, 8);
            if ((lane & 15) == 0) s_l[w][g * 16 + (lane >> 4) * 4 + r] = v;
        }
    __syncthreads();
    if (tid < 64) {
        float v = s_l[0][tid] + s_l[1][tid] + s_l[2][tid] + s_l[3][tid];
        ((float*)(ws + OFF_L))[q * N_SRC + row0 + tid] = v;
    }
}

// k3: 32 blocks; one row per thread; last block finalizes (fence+counter).
__global__ __launch_bounds__(256) void k3_final(const char* __restrict__ ws,
                                                float* __restrict__ out) {
    const int tid = threadIdx.x;
    const int b   = blockIdx.x;

    __shared__ float s0[256], s1[256];
    // reduce PART -> ssq (needed by every block for A_i), spsi (last block)
    {
        float2 p = ((const float2*)(ws + OFF_PART))[tid];
        s0[tid] = p.x; s1[tid] = p.y;
    }
    __syncthreads();
    for (int off = 128; off > 0; off >>= 1) {
        if (tid < off) { s0[tid] += s0[tid + off]; s1[tid] += s1[tid + off]; }
        __syncthreads();
    }
    const float ssq  = s0[0];
    const float spsi = s1[0];
    __syncthreads();

    const float inv_cn = (float)M_TGT / ssq;
    const float logM   = logf((float)M_TGT);
    const float* __restrict__ L   = (const float*)(ws + OFF_L);
    const float* __restrict__ sqs = (const float*)(ws + OFF_SQS);

    const int i = b * 256 + tid;
    float lt = 0.f;
#pragma unroll
    for (int qq = 0; qq < QSPLIT; ++qq) lt += L[qq * N_SRC + i];
    const float A = -sqs[i] * inv_cn * (1.0f / REG_P) - logM;
    float val = -REG_P * (A + LN2 * __log2f(lt));

    s0[tid] = val;
    __syncthreads();
    for (int off = 128; off > 0; off >>= 1) {
        if (tid < off) s0[tid] += s0[tid + off];
        __syncthreads();
    }
    if (tid == 0) {
        float* ACC = (float*)(ws + OFF_ACC);
        unsigned* CNT = (unsigned*)(ws + OFF_CNT);
        atomicAdd(ACC, s0[0]);
        __threadfence();
        unsigned old = atomicAdd(CNT, 1u);
        if (old == 31u) {
            __threadfence();
            float total = atomicAdd(ACC, 0.f);   // atomic read: all 32 adds visible
            out[0] = total / (float)N_SRC + spsi / (float)M_TGT;
        }
    }
}

extern "C" void kernel_launch(void* const* d_in, const int* in_sizes, int n_in,
                              void* d_out, int out_size, void* d_ws, size_t ws_size,
                              hipStream_t stream) {
    const float* src = (const float*)d_in[0];   // [N, D]
    const float* tgt = (const float*)d_in[1];   // [M, D]
    const float* psi = (const float*)d_in[2];   // [M]
    char*  ws  = (char*)d_ws;
    float* out = (float*)d_out;

    k1_stage<<<384, 256, 0, stream>>>(src, tgt, psi, ws);
    k2_main<<<(N_SRC / 64) * QSPLIT, 256, 0, stream>>>(src, psi, ws);
    k3_final<<<32, 256, 0, stream>>>(ws, out);
}

// Round 8
// 238.442 us; speedup vs baseline: 1.0515x; 1.0515x over previous
//
#include <hip/hip_runtime.h>
#include <math.h>

#define N_SRC 8192
#define M_TGT 16384
#define REG_P 0.05f
#define LOG2E 1.44269504088896340736f
#define LN2   0.69314718055994530942f

#define QSPLIT 16                 // k2: 128 rowblks x 16 = 2048 blocks
#define K1_BLOCKS 384

typedef __attribute__((ext_vector_type(8))) short short8;
typedef __attribute__((ext_vector_type(4))) float f32x4;

// Workspace byte offsets
#define OFF_TGT  0u                          // staged tgt bf16, B-frag order: 2 MB
#define OFF_SQT  (2u << 20)                  // sq_t[M]: 64 KB
#define OFF_SQS  ((2u << 20) + 65536u)       // sq_s[N]: 32 KB
#define OFF_PART ((2u << 20) + 98304u)       // float2[384] block partials: 3 KB
#define OFF_ACC  ((2u << 20) + 101376u)      // float accumulator (k3)
#define OFF_CNT  ((2u << 20) + 101380u)      // uint done-counter (k3)
#define OFF_L    ((2u << 20) + 102400u)      // l partials [QSPLIT][N]: 512 KB

__device__ __forceinline__ unsigned short f2bf(float f) {   // RNE fp32->bf16
    unsigned u = __float_as_uint(f);
    u += 0x7fffu + ((u >> 16) & 1u);
    return (unsigned short)(u >> 16);
}

__device__ __forceinline__ float fast_exp2(float x) {
#if __has_builtin(__builtin_amdgcn_exp2f)
    return __builtin_amdgcn_exp2f(x);
#else
    return exp2f(x);
#endif
}

// k1: stage tgt bf16 in B-frag order (lane-contiguous 1KB stores/wave), sq_t,
// sq_s, per-block partial sums of (sq_t, psi). Proven in R3/R6 (FETCH-clean).
__global__ __launch_bounds__(256) void k1_stage(const float* __restrict__ src,
                                                const float* __restrict__ tgt,
                                                const float* __restrict__ psi,
                                                char* __restrict__ ws) {
    const int tid  = threadIdx.x;
    const int wave = tid >> 6;
    const int lane = tid & 63;
    const int lo   = lane & 15;
    const int hi   = lane >> 4;
    const int task = blockIdx.x * 4 + wave;   // 0..1535

    if (blockIdx.x == 0 && tid == 0) {        // init k3's accumulator/counter
        *(float*)(ws + OFF_ACC) = 0.f;
        *(unsigned*)(ws + OFF_CNT) = 0u;
    }

    float sq_contrib = 0.f, ps_contrib = 0.f;
    if (task < 1024) {                        // tgt tile
        const int T = task, j = T * 16 + lo;
        float sq = 0.f;
#pragma unroll
        for (int kk = 0; kk < 2; ++kk) {
            const float* p = tgt + (size_t)j * 64 + kk * 32 + hi * 8;
            float4 v0 = ((const float4*)p)[0];
            float4 v1 = ((const float4*)p)[1];
            short8 pk;
            pk[0]=(short)f2bf(v0.x); pk[1]=(short)f2bf(v0.y); pk[2]=(short)f2bf(v0.z); pk[3]=(short)f2bf(v0.w);
            pk[4]=(short)f2bf(v1.x); pk[5]=(short)f2bf(v1.y); pk[6]=(short)f2bf(v1.z); pk[7]=(short)f2bf(v1.w);
            ((short8*)(ws + OFF_TGT))[(T * 2 + kk) * 64 + lane] = pk;   // 1KB dense/wave
            sq += v0.x*v0.x + v0.y*v0.y + v0.z*v0.z + v0.w*v0.w
                + v1.x*v1.x + v1.y*v1.y + v1.z*v1.z + v1.w*v1.w;
        }
        float r = sq;
        r += __shfl_xor(r, 16); r += __shfl_xor(r, 32);
        if (hi == 0) {
            ((float*)(ws + OFF_SQT))[j] = r;
            ps_contrib = psi[j];
        }
        sq_contrib = sq;
    } else {                                  // src row norms only
        const int i = (task - 1024) * 16 + lo;
        float sq = 0.f;
#pragma unroll
        for (int kk = 0; kk < 2; ++kk) {
            const float* p = src + (size_t)i * 64 + kk * 32 + hi * 8;
            float4 v0 = ((const float4*)p)[0];
            float4 v1 = ((const float4*)p)[1];
            sq += v0.x*v0.x + v0.y*v0.y + v0.z*v0.z + v0.w*v0.w
                + v1.x*v1.x + v1.y*v1.y + v1.z*v1.z + v1.w*v1.w;
        }
        float r = sq;
        r += __shfl_xor(r, 16); r += __shfl_xor(r, 32);
        if (hi == 0) ((float*)(ws + OFF_SQS))[i] = r;
    }

    float a = sq_contrib, bb = ps_contrib;
#pragma unroll
    for (int off = 1; off < 64; off <<= 1) { a += __shfl_xor(a, off); bb += __shfl_xor(bb, off); }
    __shared__ float s_a[4], s_b[4];
    if (lane == 0) { s_a[wave] = a; s_b[wave] = bb; }
    __syncthreads();
    if (tid == 0) {
        float2 o;
        o.x = s_a[0] + s_a[1] + s_a[2] + s_a[3];
        o.y = s_b[0] + s_b[1] + s_b[2] + s_b[3];
        ((float2*)(ws + OFF_PART))[blockIdx.x] = o;
    }
}

// k2: MFMA GEMM + sum-exp2 (R6 structure, FETCH-clean frag-order B reads) with
// __launch_bounds__(256,4): cap VGPR at 128 -> 4 blocks/CU (R6 had 176/10.8%).
__global__ __launch_bounds__(256, 4) void k2_main(const float* __restrict__ src,
                                                  const float* __restrict__ psi,
                                                  char* __restrict__ ws) {
    const int tid  = threadIdx.x;
    const int lane = tid & 63;
    const int w    = tid >> 6;
    const int lo   = lane & 15;
    const int hi   = lane >> 4;
    const int q      = blockIdx.x & (QSPLIT - 1);
    const int rowblk = blockIdx.x >> 4;
    const int row0   = rowblk * 64;

    __shared__ float s_bias[1024];
    __shared__ float s_l[4][64];

    // sum sq_t from k1 partials (384 entries, 6 per lane)
    const float2* __restrict__ part = (const float2*)(ws + OFF_PART);
    float ssq = 0.f;
#pragma unroll
    for (int k = 0; k < K1_BLOCKS / 64; ++k) ssq += part[k * 64 + lane].x;
#pragma unroll
    for (int off = 1; off < 64; off <<= 1) ssq += __shfl_xor(ssq, off);
    const float inv_cn = (float)M_TGT / ssq;
    const float c_psi  = (1.0f / REG_P) * LOG2E;
    const float c_sqt  = inv_cn * c_psi;
    const float alpha2 = 2.0f * c_sqt;

    // A fragments from global fp32, pre-scaled by alpha2
    short8 Af[4][2];
#pragma unroll
    for (int g = 0; g < 4; ++g)
#pragma unroll
        for (int kk = 0; kk < 2; ++kk) {
            const float* p = src + (size_t)(row0 + g * 16 + lo) * 64 + kk * 32 + hi * 8;
            float4 u0 = ((const float4*)p)[0];
            float4 u1 = ((const float4*)p)[1];
            short8 pk;
            pk[0]=(short)f2bf(alpha2*u0.x); pk[1]=(short)f2bf(alpha2*u0.y);
            pk[2]=(short)f2bf(alpha2*u0.z); pk[3]=(short)f2bf(alpha2*u0.w);
            pk[4]=(short)f2bf(alpha2*u1.x); pk[5]=(short)f2bf(alpha2*u1.y);
            pk[6]=(short)f2bf(alpha2*u1.z); pk[7]=(short)f2bf(alpha2*u1.w);
            Af[g][kk] = pk;
        }

    // bias table for this block's 1024 cols
    {
        const float* SQT = (const float*)(ws + OFF_SQT);
        const int j0 = q * 1024 + tid * 4;
        float4 sa = *(const float4*)(SQT + j0);
        float4 pa = *(const float4*)(psi + j0);
        float4 o0;
        o0.x = pa.x * c_psi - sa.x * c_sqt;  o0.y = pa.y * c_psi - sa.y * c_sqt;
        o0.z = pa.z * c_psi - sa.z * c_sqt;  o0.w = pa.w * c_psi - sa.w * c_sqt;
        *(float4*)&s_bias[tid * 4] = o0;
    }
    __syncthreads();

    float lsum[4][4];
#pragma unroll
    for (int g = 0; g < 4; ++g)
#pragma unroll
        for (int r = 0; r < 4; ++r) lsum[g][r] = 0.f;

    // B fragments: frag-order -> each load is 64 lanes x 16B dense (1 KB)
    const short8* __restrict__ TG = (const short8*)(ws + OFF_TGT);
    const int Tbase = q * 64 + w * 16;   // this wave's 16 col-tiles
    const int colb  = w * 256 + lo;      // LDS bias base

    short8 B0n = TG[(Tbase * 2 + 0) * 64 + lane];
    short8 B1n = TG[(Tbase * 2 + 1) * 64 + lane];
    float  bln = s_bias[colb];

    for (int t = 0; t < 16; ++t) {
        short8 B0 = B0n, B1 = B1n;
        float  bl = bln;
        if (t < 15) {
            B0n = TG[((Tbase + t + 1) * 2 + 0) * 64 + lane];
            B1n = TG[((Tbase + t + 1) * 2 + 1) * 64 + lane];
            bln = s_bias[colb + (t + 1) * 16];
        }
        f32x4 bias4 = {bl, bl, bl, bl};   // C operand: bias per col (col = lane&15)
        f32x4 acc[4];
#pragma unroll
        for (int g = 0; g < 4; ++g) {
            f32x4 a = __builtin_amdgcn_mfma_f32_16x16x32_bf16(Af[g][0], B0, bias4, 0, 0, 0);
            a       = __builtin_amdgcn_mfma_f32_16x16x32_bf16(Af[g][1], B1, a,     0, 0, 0);
            acc[g] = a;
        }
#pragma unroll
        for (int g = 0; g < 4; ++g)
#pragma unroll
            for (int r = 0; r < 4; ++r)
                lsum[g][r] += fast_exp2(acc[g][r]);
    }

    // reduce over 16 col-lanes per row; combine 4 waves via LDS; write q-slice
#pragma unroll
    for (int g = 0; g < 4; ++g)
#pragma unroll
        for (int r = 0; r < 4; ++r) {
            float v = lsum[g][r];
            v += __shfl_xor(v, 1); v += __shfl_xor(v, 2);
            v += __shfl_xor(v, 4); v += __shfl_xor(v, 8);
            if ((lane & 15) == 0) s_l[w][g * 16 + (lane >> 4) * 4 + r] = v;
        }
    __syncthreads();
    if (tid < 64) {
        float v = s_l[0][tid] + s_l[1][tid] + s_l[2][tid] + s_l[3][tid];
        ((float*)(ws + OFF_L))[q * N_SRC + row0 + tid] = v;
    }
}

// k3: 32 blocks; one row per thread; last block finalizes (fence+counter).
// Proven correct in R7 (absmax 0.0).
__global__ __launch_bounds__(256) void k3_final(const char* __restrict__ ws,
                                                float* __restrict__ out) {
    const int tid = threadIdx.x;
    const int b   = blockIdx.x;

    __shared__ float s0[256], s1[256];
    {
        float2 p = ((const float2*)(ws + OFF_PART))[tid];
        float ax = p.x, ay = p.y;
        if (tid < K1_BLOCKS - 256) {
            float2 p2 = ((const float2*)(ws + OFF_PART))[256 + tid];
            ax += p2.x; ay += p2.y;
        }
        s0[tid] = ax; s1[tid] = ay;
    }
    __syncthreads();
    for (int off = 128; off > 0; off >>= 1) {
        if (tid < off) { s0[tid] += s0[tid + off]; s1[tid] += s1[tid + off]; }
        __syncthreads();
    }
    const float ssq  = s0[0];
    const float spsi = s1[0];
    __syncthreads();

    const float inv_cn = (float)M_TGT / ssq;
    const float logM   = logf((float)M_TGT);
    const float* __restrict__ L   = (const float*)(ws + OFF_L);
    const float* __restrict__ sqs = (const float*)(ws + OFF_SQS);

    const int i = b * 256 + tid;
    float lt = 0.f;
#pragma unroll
    for (int qq = 0; qq < QSPLIT; ++qq) lt += L[qq * N_SRC + i];
    const float A = -sqs[i] * inv_cn * (1.0f / REG_P) - logM;
    float val = -REG_P * (A + LN2 * __log2f(lt));

    s0[tid] = val;
    __syncthreads();
    for (int off = 128; off > 0; off >>= 1) {
        if (tid < off) s0[tid] += s0[tid + off];
        __syncthreads();
    }
    if (tid == 0) {
        float* ACC = (float*)(ws + OFF_ACC);
        unsigned* CNT = (unsigned*)(ws + OFF_CNT);
        atomicAdd(ACC, s0[0]);
        __threadfence();
        unsigned old = atomicAdd(CNT, 1u);
        if (old == 31u) {
            __threadfence();
            float total = atomicAdd(ACC, 0.f);   // atomic read: all 32 adds visible
            out[0] = total / (float)N_SRC + spsi / (float)M_TGT;
        }
    }
}

extern "C" void kernel_launch(void* const* d_in, const int* in_sizes, int n_in,
                              void* d_out, int out_size, void* d_ws, size_t ws_size,
                              hipStream_t stream) {
    const float* src = (const float*)d_in[0];   // [N, D]
    const float* tgt = (const float*)d_in[1];   // [M, D]
    const float* psi = (const float*)d_in[2];   // [M]
    char*  ws  = (char*)d_ws;
    float* out = (float*)d_out;

    k1_stage<<<K1_BLOCKS, 256, 0, stream>>>(src, tgt, psi, ws);
    k2_main<<<(N_SRC / 64) * QSPLIT, 256, 0, stream>>>(src, psi, ws);
    k3_final<<<32, 256, 0, stream>>>(ws, out);
}